// Round 6
// baseline (660.426 us; speedup 1.0000x reference)
//
#include <hip/hip_runtime.h>
#include <math.h>

// VanillaRNN via MFMA: B=1024, T=512, I=64, H=128, O=10, fp32 in/out.
// R13: 8 homogeneous waves x 16 columns each (was R8: 4 consumers x 32 cols
// + 4 producers).
//  - R12 post-mortem: wall = 512 x per-step latency; per-step ~= serial
//    chain (~750) + per-SIMD issue (R8: 639 cyc, tanh-dominated). Dual-chain
//    raised issue superlinearly -> regressed. This round CUTS issue instead:
//    each wave owns 16 output columns -> 4 tanh/lane (was 8), 4 h-MFMAs +
//    2 x-MFMAs, self-contained R7-style tail (x-pack + x-MFMAs seeded with
//    bias, Cx in registers -> no seed LDS read post-barrier).
//  - Per-SIMD issue ~440 (was 639); post-barrier path: 4 ds_read_b128 ->
//    4 MFMAs (depth 2) -> add -> 4 tanh (2 shared-rcp pairs, R12-verified)
//    -> 4 b16 writes -> lgkmcnt drain -> barrier.
//  - All fragment maps are R7/R8/R12-verified; only column ownership
//    changes: n = 16*wave + c (one col per lane), writes are scalar b16.
//  - 64 blocks x 512 threads, LDS-only barrier (no vmcnt drain), depth-2
//    raw-x prefetch. h ping-pong PITCH=136.

#define T_STEPS 512
#define I_DIM   64
#define H_DIM   128
#define O_DIM   10
#define BT      16            // batch rows per block
#define PITCH   136           // bf16 elements per h row

typedef short  bf16x8 __attribute__((ext_vector_type(8)));
typedef float  f32x4  __attribute__((ext_vector_type(4)));

#define MFMA(A, Bi, C) __builtin_amdgcn_mfma_f32_16x16x32_bf16(                 \
    __builtin_bit_cast(bf16x8, (A)), __builtin_bit_cast(bf16x8, (Bi)), (C), 0, 0, 0)

static __device__ inline short f2bf(float f) {               // full RNE (preload only)
    union { float f; unsigned u; } v; v.f = f;
    unsigned r = v.u + 0x7FFFu + ((v.u >> 16) & 1u);
    return (short)(r >> 16);
}
static __device__ inline short rbf(float f) {                // fast round (2 ops)
    return (short)((__builtin_bit_cast(unsigned, f) + 0x8000u) >> 16);
}
static __device__ inline int pk2(float a, float b) {         // fast packed round
    unsigned ua = __builtin_bit_cast(unsigned, a);
    unsigned ub = __builtin_bit_cast(unsigned, b);
    return (int)(((ua + 0x8000u) >> 16) | ((ub + 0x8000u) & 0xFFFF0000u));
}
static __device__ inline float bf2f(short s) {
    union { unsigned u; float f; } v; v.u = ((unsigned)(unsigned short)s) << 16;
    return v.f;
}
static __device__ inline int4 load_frag(const float* src) {  // f32 row -> bf16x8 frag
    short e[8];
    #pragma unroll
    for (int j = 0; j < 8; ++j) e[j] = f2bf(src[j]);
    int4 r;
    r.x = ((int)(unsigned short)e[0]) | ((int)(unsigned short)e[1] << 16);
    r.y = ((int)(unsigned short)e[2]) | ((int)(unsigned short)e[3] << 16);
    r.z = ((int)(unsigned short)e[4]) | ((int)(unsigned short)e[5] << 16);
    r.w = ((int)(unsigned short)e[6]) | ((int)(unsigned short)e[7] << 16);
    return r;
}
// Barrier that does NOT drain vmcnt: h handoff only needs LDS ops complete.
static __device__ inline void lds_barrier() {
    asm volatile("s_waitcnt lgkmcnt(0)\n\ts_barrier" ::: "memory");
}

// One step. Entry: Cx holds x-part + bias of THIS step for col n (4 rows).
// Body: 4 h-MFMAs, 4 tanh (Pade[3/3], shared rcp per pair - R12-verified),
// 4 b16 writes. Tail: pack next x, 2 x-MFMAs for next Cx, reload XR <- x_TN.
#define RNN_STEP(P, XR, TN)                                                     \
    {                                                                           \
        const short* hb = hbuf[P] + c * PITCH + q * 8;                          \
        bf16x8 Ah0 = *(const bf16x8*)(hb +  0);                                 \
        bf16x8 Ah1 = *(const bf16x8*)(hb + 32);                                 \
        bf16x8 Ah2 = *(const bf16x8*)(hb + 64);                                 \
        bf16x8 Ah3 = *(const bf16x8*)(hb + 96);                                 \
        f32x4 Ca = Cx;                                                          \
        f32x4 Cb = {0.f, 0.f, 0.f, 0.f};                                        \
        Ca = MFMA(Ah0, BW[0], Ca);                                              \
        Cb = MFMA(Ah1, BW[1], Cb);                                              \
        Ca = MFMA(Ah2, BW[2], Ca);                                              \
        Cb = MFMA(Ah3, BW[3], Cb);                                              \
        const f32x4 C = Ca + Cb;                                                \
        short* hw = hbuf[1 - (P)];                                              \
        _Pragma("unroll")                                                       \
        for (int pr = 0; pr < 2; ++pr) {                                        \
            const float z0 = C[2 * pr], z1 = C[2 * pr + 1];                     \
            const float t0 = z0 * z0, t1 = z1 * z1;                             \
            const float p0 = fmaf(fmaf(t0 + 378.f, t0, 17325.f), t0, 135135.f); \
            const float p1 = fmaf(fmaf(t1 + 378.f, t1, 17325.f), t1, 135135.f); \
            const float q0 = fmaf(fmaf(fmaf(28.f, t0, 3150.f), t0, 62370.f), t0, 135135.f); \
            const float q1 = fmaf(fmaf(fmaf(28.f, t1, 3150.f), t1, 62370.f), t1, 135135.f); \
            const float rr = __builtin_amdgcn_rcpf(q0 * q1);                    \
            const float h0 = __builtin_amdgcn_fmed3f(z0 * p0 * (rr * q1), -1.f, 1.f); \
            const float h1 = __builtin_amdgcn_fmed3f(z1 * p1 * (rr * q0), -1.f, 1.f); \
            hw[(q * 4 + 2 * pr    ) * PITCH + n] = rbf(h0);                     \
            hw[(q * 4 + 2 * pr + 1) * PITCH + n] = rbf(h1);                     \
        }                                                                       \
        /* ---- tail: x-part of the NEXT step (independent of h) */             \
        {                                                                       \
            int4 ax0, ax1;                                                      \
            ax0.x = pk2(XR[0].x, XR[0].y); ax0.y = pk2(XR[0].z, XR[0].w);       \
            ax0.z = pk2(XR[1].x, XR[1].y); ax0.w = pk2(XR[1].z, XR[1].w);       \
            ax1.x = pk2(XR[2].x, XR[2].y); ax1.y = pk2(XR[2].z, XR[2].w);       \
            ax1.z = pk2(XR[3].x, XR[3].y); ax1.w = pk2(XR[3].z, XR[3].w);       \
            const int tn = ((TN) < T_STEPS) ? (TN) : (T_STEPS - 1);             \
            const float* pn = xrow + (size_t)tn * I_DIM;                        \
            XR[0] = *(const float4*)(pn +      q * 8);                          \
            XR[1] = *(const float4*)(pn +      q * 8 + 4);                      \
            XR[2] = *(const float4*)(pn + 32 + q * 8);                          \
            XR[3] = *(const float4*)(pn + 32 + q * 8 + 4);                      \
            Cx = MFMA(ax0, BX[0], biasv);                                       \
            Cx = MFMA(ax1, BX[1], Cx);                                          \
        }                                                                       \
        lds_barrier();                                                          \
    }

__global__ __launch_bounds__(512, 2)
void rnn_mfma_kernel(
    const float* __restrict__ x,      // [B, T, I]
    const float* __restrict__ W_hx,   // [H, I]
    const float* __restrict__ W_hh,   // [H, H]
    const float* __restrict__ b_hh,   // [H]
    const float* __restrict__ W_ph,   // [O, H]
    const float* __restrict__ b_ph,   // [O]
    float* __restrict__ out)          // [B, O]
{
    const int b0   = blockIdx.x * BT;
    const int tid  = threadIdx.x;
    const int wave = tid >> 6;        // 0..7 -> cols [16*wave, 16*wave+16)
    const int lane = tid & 63;
    const int c    = lane & 15;
    const int q    = lane >> 4;
    const int n    = wave * 16 + c;   // the ONE output column this lane owns

    __shared__ __align__(16) short hbuf[2][BT * PITCH];   // bf16 h, ping-pong

    // ---- Pinned B-operand weights for column n (R7/R8-verified layout):
    // BW[kt] = W_hh[n][kt*32 + 8q..+7], BX[kx] = W_hx[n][kx*32 + 8q..+7].
    int4 BW[4], BX[2];
    #pragma unroll
    for (int kt = 0; kt < 4; ++kt)
        BW[kt] = load_frag(W_hh + n * H_DIM + kt * 32 + q * 8);
    #pragma unroll
    for (int kx = 0; kx < 2; ++kx)
        BX[kx] = load_frag(W_hx + n * I_DIM + kx * 32 + q * 8);
    #pragma unroll
    for (int kt = 0; kt < 4; ++kt)
        asm volatile("" : "+v"(BW[kt].x), "+v"(BW[kt].y), "+v"(BW[kt].z), "+v"(BW[kt].w));
    #pragma unroll
    for (int kx = 0; kx < 2; ++kx)
        asm volatile("" : "+v"(BX[kx].x), "+v"(BX[kx].y), "+v"(BX[kx].z), "+v"(BX[kx].w));

    const float bb = b_hh[n];
    const f32x4 biasv = {bb, bb, bb, bb};

    // ---- h0 = 0 (both planes, cheap)
    for (int idx = tid; idx < 2 * BT * PITCH; idx += 512) ((short*)hbuf)[idx] = 0;

    // ---- Depth-2 raw-x prefetch (R7-verified): lane c owns batch row b0+c.
    const float* xrow = x + (size_t)(b0 + c) * T_STEPS * I_DIM;
    float4 xrA[4], xrB[4];
    {
        const float* p0 = xrow;
        xrA[0] = *(const float4*)(p0 +      q * 8);
        xrA[1] = *(const float4*)(p0 +      q * 8 + 4);
        xrA[2] = *(const float4*)(p0 + 32 + q * 8);
        xrA[3] = *(const float4*)(p0 + 32 + q * 8 + 4);
        const float* p1 = xrow + I_DIM;
        xrB[0] = *(const float4*)(p1 +      q * 8);
        xrB[1] = *(const float4*)(p1 +      q * 8 + 4);
        xrB[2] = *(const float4*)(p1 + 32 + q * 8);
        xrB[3] = *(const float4*)(p1 + 32 + q * 8 + 4);
    }

    // ---- Pre-loop: Cx for step 0 from xrA (= x_0); reissue xrA <- x_2.
    f32x4 Cx;
    {
        int4 ax0, ax1;
        ax0.x = pk2(xrA[0].x, xrA[0].y); ax0.y = pk2(xrA[0].z, xrA[0].w);
        ax0.z = pk2(xrA[1].x, xrA[1].y); ax0.w = pk2(xrA[1].z, xrA[1].w);
        ax1.x = pk2(xrA[2].x, xrA[2].y); ax1.y = pk2(xrA[2].z, xrA[2].w);
        ax1.z = pk2(xrA[3].x, xrA[3].y); ax1.w = pk2(xrA[3].z, xrA[3].w);
        const float* p2 = xrow + 2 * I_DIM;
        xrA[0] = *(const float4*)(p2 +      q * 8);
        xrA[1] = *(const float4*)(p2 +      q * 8 + 4);
        xrA[2] = *(const float4*)(p2 + 32 + q * 8);
        xrA[3] = *(const float4*)(p2 + 32 + q * 8 + 4);
        Cx = MFMA(ax0, BX[0], biasv);
        Cx = MFMA(ax1, BX[1], Cx);
    }
    __syncthreads();   // once, outside the loop

    #pragma unroll 1
    for (int t = 0; t < T_STEPS; t += 2) {
        RNN_STEP(0, xrB, t + 3)   // step t:   Cx(x_t);   tail preps Cx(x_{t+1}), xrB <- x_{t+3}
        RNN_STEP(1, xrA, t + 4)   // step t+1: Cx(x_{t+1}); tail preps Cx(x_{t+2}), xrA <- x_{t+4}
    }

    // ---- Epilogue: final h_512 sits in hbuf[0] (t=511 odd writes plane 0).
    if (tid < BT * O_DIM) {
        const int m = tid / O_DIM;
        const int o = tid % O_DIM;
        float acc = b_ph[o];
        #pragma unroll 4
        for (int k = 0; k < H_DIM; ++k)
            acc = fmaf(W_ph[o * H_DIM + k], bf2f(hbuf[0][m * PITCH + k]), acc);
        out[(size_t)(b0 + m) * O_DIM + o] = acc;
    }
}

extern "C" void kernel_launch(void* const* d_in, const int* in_sizes, int n_in,
                              void* d_out, int out_size, void* d_ws, size_t ws_size,
                              hipStream_t stream) {
    const float* x    = (const float*)d_in[0];
    const float* W_hx = (const float*)d_in[1];
    const float* W_hh = (const float*)d_in[2];
    const float* b_hh = (const float*)d_in[3];
    const float* W_ph = (const float*)d_in[4];
    const float* b_ph = (const float*)d_in[5];
    float* out = (float*)d_out;

    rnn_mfma_kernel<<<1024 / BT, 512, 0, stream>>>(x, W_hx, W_hh, b_hh, W_ph, b_ph, out);
}

// Round 7
// 467.004 us; speedup vs baseline: 1.4142x; 1.4142x over previous
//
#include <hip/hip_runtime.h>
#include <math.h>

// VanillaRNN via MFMA: B=1024, T=512, I=64, H=128, O=10, fp32 in/out.
// R14: back to the verified-best R8 structure (326us rocprof), minus its two
// measured inefficiencies. R12/R13 post-mortem: both lockstep-homogeneous
// structures landed at 2438 cyc/step (vs R8 1529) - phase-diverse
// producer/consumer asymmetry is what makes R8's overlap work. Keep it.
//  - 512 threads = 8 waves. Waves 0-3 (consumers) run the h-recurrence:
//    barrier -> ds_read h-frags + xproj seed -> 8 MFMAs -> tanh -> packed
//    b32 h-writes -> barrier. No vmem on the critical path.
//  - Waves 4-7 (producers) compute xproj(t+1)+bias into an LDS ring one step
//    ahead (depth-2 raw-x prefetch). One consumer + one producer per SIMD.
//  - FIX 1 (new): XPITCH 20 -> 18. Seed reads/writes strided 2*XPITCH words
//    = 40 ==> bank stride 8 ==> 4-way conflict ON the post-barrier path
//    (R8 measured 4.2M conflicts vs R7 2.1M). Stride 36 == 4 (mod 32) ==>
//    2-way only (free). Alignment holds: n0 even => base 16B-aligned.
//  - FIX 2 (new): consumer tanh uses the R12-verified shared-rcp pair trick
//    (rr = rcp(q0*q1); 1/q0 = rr*q1): 8 -> 4 v_rcp_f32 per step/lane.
//  - Everything else byte-identical to R8: paired-column B-frags, Pade[3/3]
//    tanh + med3 clamp, pk2 packed h-writes, bias folded into producer seed,
//    LDS-only barrier (no vmcnt drain), setprio(1) on consumers.

#define T_STEPS 512
#define I_DIM   64
#define H_DIM   128
#define O_DIM   10
#define BT      16            // batch rows per block
#define PITCH   136           // bf16 elements per h row
#define XPITCH  18            // f32 per xproj row: stride 2*18=36==4 mod 32 (2-way)

typedef short  bf16x8 __attribute__((ext_vector_type(8)));
typedef float  f32x4  __attribute__((ext_vector_type(4)));

#define MFMA(A, Bi, C) __builtin_amdgcn_mfma_f32_16x16x32_bf16((A), __builtin_bit_cast(bf16x8, (Bi)), (C), 0, 0, 0)

static __device__ inline short f2bf(float f) {               // full RNE (preload only)
    union { float f; unsigned u; } v; v.f = f;
    unsigned r = v.u + 0x7FFFu + ((v.u >> 16) & 1u);
    return (short)(r >> 16);
}
static __device__ inline int pk2(float a, float b) {         // fast packed round
    unsigned ua = __builtin_bit_cast(unsigned, a);
    unsigned ub = __builtin_bit_cast(unsigned, b);
    return (int)(((ua + 0x8000u) >> 16) | ((ub + 0x8000u) & 0xFFFF0000u));
}
static __device__ inline float bf2f(short s) {
    union { unsigned u; float f; } v; v.u = ((unsigned)(unsigned short)s) << 16;
    return v.f;
}
// Barrier that does NOT drain vmcnt: handoff only needs LDS ops complete.
static __device__ inline void lds_barrier() {
    asm volatile("s_waitcnt lgkmcnt(0)\n\ts_barrier" ::: "memory");
}
static __device__ inline int4 load_frag(const float* src) {  // f32 row -> bf16x8 frag
    short e[8];
    #pragma unroll
    for (int j = 0; j < 8; ++j) e[j] = f2bf(src[j]);
    int4 r;
    r.x = ((int)(unsigned short)e[0]) | ((int)(unsigned short)e[1] << 16);
    r.y = ((int)(unsigned short)e[2]) | ((int)(unsigned short)e[3] << 16);
    r.z = ((int)(unsigned short)e[4]) | ((int)(unsigned short)e[5] << 16);
    r.w = ((int)(unsigned short)e[6]) | ((int)(unsigned short)e[7] << 16);
    return r;
}

// Consumer step: h_{t+1} = tanh(xp + h_t W_hh^T). Reads hbuf[P] + xpb[P],
// writes hbuf[1-P]. Lane (c,q) owns columns n0=32w+2c and n0+1.
// tanh = Pade[3/3] with one shared rcp per pair (R12-verified).
#define CONS_STEP(P)                                                            \
    {                                                                           \
        const short* hb = hbuf[P] + c * PITCH + q * 8;                          \
        bf16x8 Ah0 = *(const bf16x8*)(hb +  0);                                 \
        bf16x8 Ah1 = *(const bf16x8*)(hb + 32);                                 \
        bf16x8 Ah2 = *(const bf16x8*)(hb + 64);                                 \
        bf16x8 Ah3 = *(const bf16x8*)(hb + 96);                                 \
        f32x4 Ca0 = *(const f32x4*)&xpb[P][ n0      * XPITCH + 4 * q];          \
        f32x4 Ca1 = *(const f32x4*)&xpb[P][(n0 + 1) * XPITCH + 4 * q];          \
        f32x4 Cb0 = {0.f, 0.f, 0.f, 0.f};                                       \
        f32x4 Cb1 = {0.f, 0.f, 0.f, 0.f};                                       \
        Ca0 = MFMA(Ah0, Bw[0][0], Ca0); Ca1 = MFMA(Ah0, Bw[1][0], Ca1);         \
        Cb0 = MFMA(Ah1, Bw[0][1], Cb0); Cb1 = MFMA(Ah1, Bw[1][1], Cb1);         \
        Ca0 = MFMA(Ah2, Bw[0][2], Ca0); Ca1 = MFMA(Ah2, Bw[1][2], Ca1);         \
        Cb0 = MFMA(Ah3, Bw[0][3], Cb0); Cb1 = MFMA(Ah3, Bw[1][3], Cb1);         \
        const f32x4 C0 = Ca0 + Cb0;                                             \
        const f32x4 C1 = Ca1 + Cb1;                                             \
        short* hw = hbuf[1 - (P)];                                              \
        _Pragma("unroll")                                                       \
        for (int r = 0; r < 4; ++r) {                                           \
            const int m = q * 4 + r;                                            \
            const float z0 = C0[r], z1 = C1[r];                                 \
            const float t0 = z0 * z0, t1 = z1 * z1;                             \
            const float p0 = fmaf(fmaf(t0 + 378.f, t0, 17325.f), t0, 135135.f); \
            const float p1 = fmaf(fmaf(t1 + 378.f, t1, 17325.f), t1, 135135.f); \
            const float q0 = fmaf(fmaf(fmaf(28.f, t0, 3150.f), t0, 62370.f), t0, 135135.f); \
            const float q1 = fmaf(fmaf(fmaf(28.f, t1, 3150.f), t1, 62370.f), t1, 135135.f); \
            const float rr = __builtin_amdgcn_rcpf(q0 * q1);                    \
            const float h0 = __builtin_amdgcn_fmed3f(z0 * p0 * (rr * q1), -1.f, 1.f); \
            const float h1 = __builtin_amdgcn_fmed3f(z1 * p1 * (rr * q0), -1.f, 1.f); \
            *(int*)(hw + m * PITCH + n0) = pk2(h0, h1);                         \
        }                                                                       \
    }

// Producer step during parity P: write xp for step t+1 into xpb[1-P] from XR
// (= x_{t+1}), then reissue XR <- x at time TN (2 steps of vmcnt slack).
#define PROD_STEP(P, XR, TN)                                                    \
    {                                                                           \
        int4 a0, a1;                                                            \
        a0.x = pk2(XR[0].x, XR[0].y); a0.y = pk2(XR[0].z, XR[0].w);             \
        a0.z = pk2(XR[1].x, XR[1].y); a0.w = pk2(XR[1].z, XR[1].w);             \
        a1.x = pk2(XR[2].x, XR[2].y); a1.y = pk2(XR[2].z, XR[2].w);             \
        a1.z = pk2(XR[3].x, XR[3].y); a1.w = pk2(XR[3].z, XR[3].w);             \
        const int tn = ((TN) < T_STEPS) ? (TN) : (T_STEPS - 1);                 \
        const float* pn = xrow + (size_t)tn * I_DIM;                            \
        XR[0] = *(const float4*)(pn +      q * 8);                              \
        XR[1] = *(const float4*)(pn +      q * 8 + 4);                          \
        XR[2] = *(const float4*)(pn + 32 + q * 8);                              \
        XR[3] = *(const float4*)(pn + 32 + q * 8 + 4);                          \
        bf16x8 Ax0 = __builtin_bit_cast(bf16x8, a0);                            \
        bf16x8 Ax1 = __builtin_bit_cast(bf16x8, a1);                            \
        f32x4 P0 = MFMA(Ax0, BX[0][0], biasv[0]);                               \
        P0 = MFMA(Ax1, BX[0][1], P0);                                           \
        f32x4 P1 = MFMA(Ax0, BX[1][0], biasv[1]);                               \
        P1 = MFMA(Ax1, BX[1][1], P1);                                           \
        *(f32x4*)&xpb[1 - (P)][ n0      * XPITCH + 4 * q] = P0;                 \
        *(f32x4*)&xpb[1 - (P)][(n0 + 1) * XPITCH + 4 * q] = P1;                 \
    }

__global__ __launch_bounds__(512, 2)
void rnn_mfma_kernel(
    const float* __restrict__ x,      // [B, T, I]
    const float* __restrict__ W_hx,   // [H, I]
    const float* __restrict__ W_hh,   // [H, H]
    const float* __restrict__ b_hh,   // [H]
    const float* __restrict__ W_ph,   // [O, H]
    const float* __restrict__ b_ph,   // [O]
    float* __restrict__ out)          // [B, O]
{
    const int b0   = blockIdx.x * BT;
    const int tid  = threadIdx.x;
    const int wave = tid >> 6;        // 0-3 consumers, 4-7 producers
    const int lane = tid & 63;
    const int c    = lane & 15;
    const int q    = lane >> 4;
    const int w    = wave & 3;        // N-slice [32w, 32w+32)
    const int n0   = w * 32 + 2 * c;  // paired columns n0, n0+1

    __shared__ __align__(16) short hbuf[2][BT * PITCH];      // bf16 h ping-pong
    __shared__ __align__(16) float xpb[2][H_DIM * XPITCH];   // xproj+bias ring

    // ---- h0 = 0
    for (int idx = tid; idx < BT * PITCH; idx += 512) hbuf[0][idx] = 0;

    if (wave < 4) {
        // ================= consumer =================
        int4 Bw[2][4];   // W_hh B-frags: [nt = column n0+nt][kt]
        #pragma unroll
        for (int nt = 0; nt < 2; ++nt)
            #pragma unroll
            for (int kt = 0; kt < 4; ++kt)
                Bw[nt][kt] = load_frag(W_hh + (n0 + nt) * H_DIM + kt * 32 + q * 8);
        #pragma unroll
        for (int nt = 0; nt < 2; ++nt)
            #pragma unroll
            for (int kt = 0; kt < 4; ++kt)
                asm volatile("" : "+v"(Bw[nt][kt].x), "+v"(Bw[nt][kt].y),
                                  "+v"(Bw[nt][kt].z), "+v"(Bw[nt][kt].w));
        __syncthreads();
        __builtin_amdgcn_s_setprio(1);     // favor the recurrence wave on the SIMD
        #pragma unroll 1
        for (int t = 0; t < T_STEPS; t += 2) {
            CONS_STEP(0)
            lds_barrier();
            CONS_STEP(1)
            lds_barrier();
        }
        __builtin_amdgcn_s_setprio(0);
    } else {
        // ================= producer =================
        int4 BX[2][2];   // W_hx B-frags
        f32x4 biasv[2];
        #pragma unroll
        for (int nt = 0; nt < 2; ++nt) {
            #pragma unroll
            for (int kx = 0; kx < 2; ++kx)
                BX[nt][kx] = load_frag(W_hx + (n0 + nt) * I_DIM + kx * 32 + q * 8);
            const float bb = b_hh[n0 + nt];
            biasv[nt] = (f32x4){bb, bb, bb, bb};
        }
        #pragma unroll
        for (int nt = 0; nt < 2; ++nt)
            #pragma unroll
            for (int kx = 0; kx < 2; ++kx)
                asm volatile("" : "+v"(BX[nt][kx].x), "+v"(BX[nt][kx].y),
                                  "+v"(BX[nt][kx].z), "+v"(BX[nt][kx].w));

        const float* xrow = x + (size_t)(b0 + c) * T_STEPS * I_DIM;
        {   // xp[0] = x_0 W_hx^T + b, before the sync
            float4 x0[4];
            x0[0] = *(const float4*)(xrow +      q * 8);
            x0[1] = *(const float4*)(xrow +      q * 8 + 4);
            x0[2] = *(const float4*)(xrow + 32 + q * 8);
            x0[3] = *(const float4*)(xrow + 32 + q * 8 + 4);
            int4 a0, a1;
            a0.x = pk2(x0[0].x, x0[0].y); a0.y = pk2(x0[0].z, x0[0].w);
            a0.z = pk2(x0[1].x, x0[1].y); a0.w = pk2(x0[1].z, x0[1].w);
            a1.x = pk2(x0[2].x, x0[2].y); a1.y = pk2(x0[2].z, x0[2].w);
            a1.z = pk2(x0[3].x, x0[3].y); a1.w = pk2(x0[3].z, x0[3].w);
            bf16x8 Ax0 = __builtin_bit_cast(bf16x8, a0);
            bf16x8 Ax1 = __builtin_bit_cast(bf16x8, a1);
            f32x4 P0 = MFMA(Ax0, BX[0][0], biasv[0]);
            P0 = MFMA(Ax1, BX[0][1], P0);
            f32x4 P1 = MFMA(Ax0, BX[1][0], biasv[1]);
            P1 = MFMA(Ax1, BX[1][1], P1);
            *(f32x4*)&xpb[0][ n0      * XPITCH + 4 * q] = P0;
            *(f32x4*)&xpb[0][(n0 + 1) * XPITCH + 4 * q] = P1;
        }
        // depth-2 raw-x prefetch: xrA <- x_1, xrB <- x_2
        float4 xrA[4], xrB[4];
        const float* p1 = xrow + I_DIM;
        xrA[0] = *(const float4*)(p1 +      q * 8);
        xrA[1] = *(const float4*)(p1 +      q * 8 + 4);
        xrA[2] = *(const float4*)(p1 + 32 + q * 8);
        xrA[3] = *(const float4*)(p1 + 32 + q * 8 + 4);
        const float* p2 = xrow + 2 * I_DIM;
        xrB[0] = *(const float4*)(p2 +      q * 8);
        xrB[1] = *(const float4*)(p2 +      q * 8 + 4);
        xrB[2] = *(const float4*)(p2 + 32 + q * 8);
        xrB[3] = *(const float4*)(p2 + 32 + q * 8 + 4);
        __syncthreads();
        #pragma unroll 1
        for (int t = 0; t < T_STEPS; t += 2) {
            PROD_STEP(0, xrA, t + 3)   // xp for t+1 from x_{t+1}; reload x_{t+3}
            lds_barrier();
            PROD_STEP(1, xrB, t + 4)   // xp for t+2 from x_{t+2}; reload x_{t+4}
            lds_barrier();
        }
    }

    // ---- Epilogue: final h_512 sits in hbuf[0].
    if (tid < BT * O_DIM) {
        const int m = tid / O_DIM;
        const int o = tid % O_DIM;
        float acc = b_ph[o];
        #pragma unroll 4
        for (int k = 0; k < H_DIM; ++k)
            acc = fmaf(W_ph[o * H_DIM + k], bf2f(hbuf[0][m * PITCH + k]), acc);
        out[(size_t)(b0 + m) * O_DIM + o] = acc;
    }
}

extern "C" void kernel_launch(void* const* d_in, const int* in_sizes, int n_in,
                              void* d_out, int out_size, void* d_ws, size_t ws_size,
                              hipStream_t stream) {
    const float* x    = (const float*)d_in[0];
    const float* W_hx = (const float*)d_in[1];
    const float* W_hh = (const float*)d_in[2];
    const float* b_hh = (const float*)d_in[3];
    const float* W_ph = (const float*)d_in[4];
    const float* b_ph = (const float*)d_in[5];
    float* out = (float*)d_out;

    rnn_mfma_kernel<<<1024 / BT, 512, 0, stream>>>(x, W_hx, W_hh, b_hh, W_ph, b_ph, out);
}

// Round 8
// 465.292 us; speedup vs baseline: 1.4194x; 1.0037x over previous
//
#include <hip/hip_runtime.h>
#include <math.h>

// VanillaRNN via MFMA: B=1024, T=512, I=64, H=128, O=10, fp32 in/out.
// R15: R8 structure + skewed producers (2 steps ahead) + register-seed
// prefetch on the consumer.
//  - R14 post-mortem: XPITCH re-stride + shared-rcp were neutral (conflicts
//    even rose; strided f32x4 xpb ops were already near the b128 floor).
//    The remaining removable piece of the consumer's post-barrier serial
//    path is the SEED READ: first MFMA needed ds_read #5/6 of the burst.
//  - Fix: producers compute xp[t+2] during step t (ring of 2, skewed;
//    prologue primes xp[0], xp[1]). Consumers prefetch next step's seed into
//    REGISTERS mid-step (2 ds_reads under the tanh shadow); current step's
//    MFMAs seed from regs, so the post-barrier burst is 4 h-reads only and
//    the first MFMA waits only on Ah0.
//  - New ring layout float[2][64][36]: cp=16w+c owns cols (n0,n0+1);
//    [cp][4q+r]=xp[row 4q+r][n0], [cp][16+4q+r]=col n0+1. Producer stores
//    P0/P1 f32x4 verbatim; consumer seed = natural b128 pair. Both at the
//    8-lane/bank-group b128 floor (conflict-free).
//  - Safety: consumer reads slot 1-P while producer writes slot P (disjoint);
//    every cross-wave handoff is >= 1 barrier apart.
//  - Kept from R8/R14: paired-column B-frags, shared-rcp Pade tanh, pk2 b32
//    h-writes, LDS-only barrier, setprio(1) consumers, depth-2 x prefetch.

#define T_STEPS 512
#define I_DIM   64
#define H_DIM   128
#define O_DIM   10
#define BT      16            // batch rows per block
#define PITCH   136           // bf16 elements per h row

typedef short  bf16x8 __attribute__((ext_vector_type(8)));
typedef float  f32x4  __attribute__((ext_vector_type(4)));

#define MFMA(A, Bi, C) __builtin_amdgcn_mfma_f32_16x16x32_bf16((A), __builtin_bit_cast(bf16x8, (Bi)), (C), 0, 0, 0)

static __device__ inline short f2bf(float f) {               // full RNE (preload only)
    union { float f; unsigned u; } v; v.f = f;
    unsigned r = v.u + 0x7FFFu + ((v.u >> 16) & 1u);
    return (short)(r >> 16);
}
static __device__ inline int pk2(float a, float b) {         // fast packed round
    unsigned ua = __builtin_bit_cast(unsigned, a);
    unsigned ub = __builtin_bit_cast(unsigned, b);
    return (int)(((ua + 0x8000u) >> 16) | ((ub + 0x8000u) & 0xFFFF0000u));
}
static __device__ inline float bf2f(short s) {
    union { unsigned u; float f; } v; v.u = ((unsigned)(unsigned short)s) << 16;
    return v.f;
}
// Barrier that does NOT drain vmcnt: handoff only needs LDS ops complete.
static __device__ inline void lds_barrier() {
    asm volatile("s_waitcnt lgkmcnt(0)\n\ts_barrier" ::: "memory");
}
static __device__ inline int4 load_frag(const float* src) {  // f32 row -> bf16x8 frag
    short e[8];
    #pragma unroll
    for (int j = 0; j < 8; ++j) e[j] = f2bf(src[j]);
    int4 r;
    r.x = ((int)(unsigned short)e[0]) | ((int)(unsigned short)e[1] << 16);
    r.y = ((int)(unsigned short)e[2]) | ((int)(unsigned short)e[3] << 16);
    r.z = ((int)(unsigned short)e[4]) | ((int)(unsigned short)e[5] << 16);
    r.w = ((int)(unsigned short)e[6]) | ((int)(unsigned short)e[7] << 16);
    return r;
}

// Consumer step, parity P: MFMAs seeded from regs S0/S1 (= xp of THIS step);
// prefetch NEXT step's seed from ring slot 1-P into N0/N1 under the tanh
// shadow. Writes h_{t+1} to hbuf[1-P].
#define CONS_STEP(P, S0, S1, N0, N1)                                            \
    {                                                                           \
        const short* hb = hbuf[P] + c * PITCH + q * 8;                          \
        bf16x8 Ah0 = *(const bf16x8*)(hb +  0);                                 \
        bf16x8 Ah1 = *(const bf16x8*)(hb + 32);                                 \
        bf16x8 Ah2 = *(const bf16x8*)(hb + 64);                                 \
        bf16x8 Ah3 = *(const bf16x8*)(hb + 96);                                 \
        f32x4 Ca0 = S0, Ca1 = S1;                                               \
        f32x4 Cb0 = {0.f, 0.f, 0.f, 0.f};                                       \
        f32x4 Cb1 = {0.f, 0.f, 0.f, 0.f};                                       \
        Ca0 = MFMA(Ah0, Bw[0][0], Ca0); Ca1 = MFMA(Ah0, Bw[1][0], Ca1);         \
        Cb0 = MFMA(Ah1, Bw[0][1], Cb0); Cb1 = MFMA(Ah1, Bw[1][1], Cb1);         \
        Ca0 = MFMA(Ah2, Bw[0][2], Ca0); Ca1 = MFMA(Ah2, Bw[1][2], Ca1);         \
        Cb0 = MFMA(Ah3, Bw[0][3], Cb0); Cb1 = MFMA(Ah3, Bw[1][3], Cb1);         \
        /* prefetch next step's seed (data stable since last barrier) */        \
        N0 = *(const f32x4*)&xpring[1 - (P)][cp][4 * q];                        \
        N1 = *(const f32x4*)&xpring[1 - (P)][cp][16 + 4 * q];                   \
        const f32x4 C0 = Ca0 + Cb0;                                             \
        const f32x4 C1 = Ca1 + Cb1;                                             \
        short* hw = hbuf[1 - (P)];                                              \
        _Pragma("unroll")                                                       \
        for (int r = 0; r < 4; ++r) {                                           \
            const int m = q * 4 + r;                                            \
            const float z0 = C0[r], z1 = C1[r];                                 \
            const float t0 = z0 * z0, t1 = z1 * z1;                             \
            const float p0 = fmaf(fmaf(t0 + 378.f, t0, 17325.f), t0, 135135.f); \
            const float p1 = fmaf(fmaf(t1 + 378.f, t1, 17325.f), t1, 135135.f); \
            const float q0 = fmaf(fmaf(fmaf(28.f, t0, 3150.f), t0, 62370.f), t0, 135135.f); \
            const float q1 = fmaf(fmaf(fmaf(28.f, t1, 3150.f), t1, 62370.f), t1, 135135.f); \
            const float rr = __builtin_amdgcn_rcpf(q0 * q1);                    \
            const float h0 = __builtin_amdgcn_fmed3f(z0 * p0 * (rr * q1), -1.f, 1.f); \
            const float h1 = __builtin_amdgcn_fmed3f(z1 * p1 * (rr * q0), -1.f, 1.f); \
            *(int*)(hw + m * PITCH + n0) = pk2(h0, h1);                         \
        }                                                                       \
    }

// Producer step, parity P: pack XR (= x_{t+2}), 4 MFMAs seeded with bias,
// write xp[t+2] into ring slot P, reload XR <- x_TN (depth-2 slack).
#define PROD_STEP(P, XR, TN)                                                    \
    {                                                                           \
        int4 a0, a1;                                                            \
        a0.x = pk2(XR[0].x, XR[0].y); a0.y = pk2(XR[0].z, XR[0].w);             \
        a0.z = pk2(XR[1].x, XR[1].y); a0.w = pk2(XR[1].z, XR[1].w);             \
        a1.x = pk2(XR[2].x, XR[2].y); a1.y = pk2(XR[2].z, XR[2].w);             \
        a1.z = pk2(XR[3].x, XR[3].y); a1.w = pk2(XR[3].z, XR[3].w);             \
        const int tn = ((TN) < T_STEPS) ? (TN) : (T_STEPS - 1);                 \
        const float* pn = xrow + (size_t)tn * I_DIM;                            \
        XR[0] = *(const float4*)(pn +      q * 8);                              \
        XR[1] = *(const float4*)(pn +      q * 8 + 4);                          \
        XR[2] = *(const float4*)(pn + 32 + q * 8);                              \
        XR[3] = *(const float4*)(pn + 32 + q * 8 + 4);                          \
        bf16x8 Ax0 = __builtin_bit_cast(bf16x8, a0);                            \
        bf16x8 Ax1 = __builtin_bit_cast(bf16x8, a1);                            \
        f32x4 P0 = MFMA(Ax0, BX[0][0], biasv[0]);                               \
        P0 = MFMA(Ax1, BX[0][1], P0);                                           \
        f32x4 P1 = MFMA(Ax0, BX[1][0], biasv[1]);                               \
        P1 = MFMA(Ax1, BX[1][1], P1);                                           \
        *(f32x4*)&xpring[P][cp][4 * q]      = P0;                               \
        *(f32x4*)&xpring[P][cp][16 + 4 * q] = P1;                               \
    }

__global__ __launch_bounds__(512, 2)
void rnn_mfma_kernel(
    const float* __restrict__ x,      // [B, T, I]
    const float* __restrict__ W_hx,   // [H, I]
    const float* __restrict__ W_hh,   // [H, H]
    const float* __restrict__ b_hh,   // [H]
    const float* __restrict__ W_ph,   // [O, H]
    const float* __restrict__ b_ph,   // [O]
    float* __restrict__ out)          // [B, O]
{
    const int b0   = blockIdx.x * BT;
    const int tid  = threadIdx.x;
    const int wave = tid >> 6;        // 0-3 consumers, 4-7 producers
    const int lane = tid & 63;
    const int c    = lane & 15;
    const int q    = lane >> 4;
    const int w    = wave & 3;        // N-slice [32w, 32w+32)
    const int n0   = w * 32 + 2 * c;  // paired columns n0, n0+1
    const int cp   = 16 * w + c;      // column-pair index 0..63

    __shared__ __align__(16) short hbuf[2][BT * PITCH];   // bf16 h ping-pong
    __shared__ __align__(16) float xpring[2][64][36];     // xp ring, pair layout

    // ---- h0 = 0
    for (int idx = tid; idx < BT * PITCH; idx += 512) hbuf[0][idx] = 0;

    if (wave < 4) {
        // ================= consumer =================
        int4 Bw[2][4];   // W_hh B-frags: [nt = column n0+nt][kt]
        #pragma unroll
        for (int nt = 0; nt < 2; ++nt)
            #pragma unroll
            for (int kt = 0; kt < 4; ++kt)
                Bw[nt][kt] = load_frag(W_hh + (n0 + nt) * H_DIM + kt * 32 + q * 8);
        #pragma unroll
        for (int nt = 0; nt < 2; ++nt)
            #pragma unroll
            for (int kt = 0; kt < 4; ++kt)
                asm volatile("" : "+v"(Bw[nt][kt].x), "+v"(Bw[nt][kt].y),
                                  "+v"(Bw[nt][kt].z), "+v"(Bw[nt][kt].w));
        __syncthreads();
        // one-time: seed for step 0 from slot 0 (written in producer prologue)
        f32x4 SA0 = *(const f32x4*)&xpring[0][cp][4 * q];
        f32x4 SA1 = *(const f32x4*)&xpring[0][cp][16 + 4 * q];
        f32x4 SB0, SB1;
        __builtin_amdgcn_s_setprio(1);     // favor the recurrence wave
        #pragma unroll 1
        for (int t = 0; t < T_STEPS; t += 2) {
            CONS_STEP(0, SA0, SA1, SB0, SB1)   // uses xp[t],   prefetches xp[t+1]
            lds_barrier();
            CONS_STEP(1, SB0, SB1, SA0, SA1)   // uses xp[t+1], prefetches xp[t+2]
            lds_barrier();
        }
        __builtin_amdgcn_s_setprio(0);
    } else {
        // ================= producer =================
        int4 BX[2][2];   // W_hx B-frags
        f32x4 biasv[2];
        #pragma unroll
        for (int nt = 0; nt < 2; ++nt) {
            #pragma unroll
            for (int kx = 0; kx < 2; ++kx)
                BX[nt][kx] = load_frag(W_hx + (n0 + nt) * I_DIM + kx * 32 + q * 8);
            const float bb = b_hh[n0 + nt];
            biasv[nt] = (f32x4){bb, bb, bb, bb};
        }
        #pragma unroll
        for (int nt = 0; nt < 2; ++nt)
            #pragma unroll
            for (int kx = 0; kx < 2; ++kx)
                asm volatile("" : "+v"(BX[nt][kx].x), "+v"(BX[nt][kx].y),
                                  "+v"(BX[nt][kx].z), "+v"(BX[nt][kx].w));

        const float* xrow = x + (size_t)(b0 + c) * T_STEPS * I_DIM;
        // Prologue: xp[0] -> slot 0, xp[1] -> slot 1 (before the sync).
        #pragma unroll
        for (int s = 0; s < 2; ++s) {
            const float* ps = xrow + (size_t)s * I_DIM;
            float4 xv[4];
            xv[0] = *(const float4*)(ps +      q * 8);
            xv[1] = *(const float4*)(ps +      q * 8 + 4);
            xv[2] = *(const float4*)(ps + 32 + q * 8);
            xv[3] = *(const float4*)(ps + 32 + q * 8 + 4);
            int4 a0, a1;
            a0.x = pk2(xv[0].x, xv[0].y); a0.y = pk2(xv[0].z, xv[0].w);
            a0.z = pk2(xv[1].x, xv[1].y); a0.w = pk2(xv[1].z, xv[1].w);
            a1.x = pk2(xv[2].x, xv[2].y); a1.y = pk2(xv[2].z, xv[2].w);
            a1.z = pk2(xv[3].x, xv[3].y); a1.w = pk2(xv[3].z, xv[3].w);
            bf16x8 Ax0 = __builtin_bit_cast(bf16x8, a0);
            bf16x8 Ax1 = __builtin_bit_cast(bf16x8, a1);
            f32x4 P0 = MFMA(Ax0, BX[0][0], biasv[0]);
            P0 = MFMA(Ax1, BX[0][1], P0);
            f32x4 P1 = MFMA(Ax0, BX[1][0], biasv[1]);
            P1 = MFMA(Ax1, BX[1][1], P1);
            *(f32x4*)&xpring[s][cp][4 * q]      = P0;
            *(f32x4*)&xpring[s][cp][16 + 4 * q] = P1;
        }
        // depth-2 raw-x prefetch: xrA <- x_2, xrB <- x_3
        float4 xrA[4], xrB[4];
        const float* p2 = xrow + 2 * I_DIM;
        xrA[0] = *(const float4*)(p2 +      q * 8);
        xrA[1] = *(const float4*)(p2 +      q * 8 + 4);
        xrA[2] = *(const float4*)(p2 + 32 + q * 8);
        xrA[3] = *(const float4*)(p2 + 32 + q * 8 + 4);
        const float* p3 = xrow + 3 * I_DIM;
        xrB[0] = *(const float4*)(p3 +      q * 8);
        xrB[1] = *(const float4*)(p3 +      q * 8 + 4);
        xrB[2] = *(const float4*)(p3 + 32 + q * 8);
        xrB[3] = *(const float4*)(p3 + 32 + q * 8 + 4);
        __syncthreads();
        #pragma unroll 1
        for (int t = 0; t < T_STEPS; t += 2) {
            PROD_STEP(0, xrA, t + 4)   // xp[t+2] from xrA=x_{t+2}; reload x_{t+4}
            lds_barrier();
            PROD_STEP(1, xrB, t + 5)   // xp[t+3] from xrB=x_{t+3}; reload x_{t+5}
            lds_barrier();
        }
    }

    // ---- Epilogue: final h_512 sits in hbuf[0].
    if (tid < BT * O_DIM) {
        const int m = tid / O_DIM;
        const int o = tid % O_DIM;
        float acc = b_ph[o];
        #pragma unroll 4
        for (int k = 0; k < H_DIM; ++k)
            acc = fmaf(W_ph[o * H_DIM + k], bf2f(hbuf[0][m * PITCH + k]), acc);
        out[(size_t)(b0 + m) * O_DIM + o] = acc;
    }
}

extern "C" void kernel_launch(void* const* d_in, const int* in_sizes, int n_in,
                              void* d_out, int out_size, void* d_ws, size_t ws_size,
                              hipStream_t stream) {
    const float* x    = (const float*)d_in[0];
    const float* W_hx = (const float*)d_in[1];
    const float* W_hh = (const float*)d_in[2];
    const float* b_hh = (const float*)d_in[3];
    const float* W_ph = (const float*)d_in[4];
    const float* b_ph = (const float*)d_in[5];
    float* out = (float*)d_out;

    rnn_mfma_kernel<<<1024 / BT, 512, 0, stream>>>(x, W_hx, W_hh, b_hh, W_ph, b_ph, out);
}